// Round 1
// baseline (1844.505 us; speedup 1.0000x reference)
//
#include <hip/hip_runtime.h>
#include <hip/hip_bf16.h>

#define IN_C  128
#define HID_C 128
#define OUT_C 64

// ---------------------------------------------------------------- degree
__global__ __launch_bounds__(256) void k_deg(const int* __restrict__ dst,
                                             float* __restrict__ deg, int nE) {
  int e = blockIdx.x * 256 + threadIdx.x;
  if (e < nE) unsafeAtomicAdd(&deg[dst[e]], 1.0f);
}

// ---------------------------------------------------- edge scatter-add (atomic)
// one wave per edge: 64 lanes x float2 = 128 channels
__global__ __launch_bounds__(256) void k_scatter(const float* __restrict__ X,
                                                 const int* __restrict__ src,
                                                 const int* __restrict__ dst,
                                                 float* __restrict__ agg, int nE) {
  int w = blockIdx.x * 4 + __builtin_amdgcn_readfirstlane(threadIdx.x >> 6);
  int lane = threadIdx.x & 63;
  if (w >= nE) return;
  int s = src[w];
  int d = dst[w];
  const float2 v = ((const float2*)(X + (size_t)s * 128))[lane];
  float* ar = agg + (size_t)d * 128 + 2 * lane;
  unsafeAtomicAdd(ar, v.x);
  unsafeAtomicAdd(ar + 1, v.y);
}

// ------------------------------------------------------------- layer 1
// h = relu(agg/deg @ Wl^T + x @ Wr^T + b)
// thread = one row; wave = 64 rows; 4 waves/block each own a 32-col chunk.
// W index is wave-uniform (readfirstlane) -> scalar loads, SGPR-operand FMAs.
__global__ __launch_bounds__(256) void k_l1(
    const float* __restrict__ X, const float* __restrict__ AGG,
    const float* __restrict__ deg,
    const float* __restrict__ Wl, const float* __restrict__ Wr,
    const float* __restrict__ bias,
    float* __restrict__ H, int nRows)
{
  const int lane = threadIdx.x & 63;
  const int c0 = __builtin_amdgcn_readfirstlane(threadIdx.x >> 6) * 32;
  const int row = blockIdx.x * 64 + lane;
  const bool active = row < nRows;
  const int r = active ? row : 0;
  const float invd = 1.0f / fmaxf(deg[r], 1.0f);

  float acc[32];
#pragma unroll
  for (int c = 0; c < 32; ++c) acc[c] = 0.0f;

  const float* arow = AGG + (size_t)r * IN_C;
  const float* xrow = X   + (size_t)r * IN_C;

#pragma unroll 1
  for (int kc = 0; kc < IN_C; kc += 16) {
    float a[16];
    const float4* p4 = (const float4*)(arow + kc);
#pragma unroll
    for (int i = 0; i < 4; ++i) {
      float4 t = p4[i];
      a[4*i+0] = t.x * invd; a[4*i+1] = t.y * invd;
      a[4*i+2] = t.z * invd; a[4*i+3] = t.w * invd;
    }
#pragma unroll
    for (int k = 0; k < 16; ++k)
#pragma unroll
      for (int c = 0; c < 32; ++c)
        acc[c] = fmaf(a[k], Wl[(c0 + c) * IN_C + kc + k], acc[c]);
  }

#pragma unroll 1
  for (int kc = 0; kc < IN_C; kc += 16) {
    float a[16];
    const float4* p4 = (const float4*)(xrow + kc);
#pragma unroll
    for (int i = 0; i < 4; ++i) {
      float4 t = p4[i];
      a[4*i+0] = t.x; a[4*i+1] = t.y; a[4*i+2] = t.z; a[4*i+3] = t.w;
    }
#pragma unroll
    for (int k = 0; k < 16; ++k)
#pragma unroll
      for (int c = 0; c < 32; ++c)
        acc[c] = fmaf(a[k], Wr[(c0 + c) * IN_C + kc + k], acc[c]);
  }

  if (active) {
    float* hrow = H + (size_t)row * HID_C + c0;
#pragma unroll
    for (int i = 0; i < 8; ++i) {
      float4 o;
      o.x = fmaxf(acc[4*i+0] + bias[c0+4*i+0], 0.0f);
      o.y = fmaxf(acc[4*i+1] + bias[c0+4*i+1], 0.0f);
      o.z = fmaxf(acc[4*i+2] + bias[c0+4*i+2], 0.0f);
      o.w = fmaxf(acc[4*i+3] + bias[c0+4*i+3], 0.0f);
      ((float4*)hrow)[i] = o;
    }
  }
}

// ------------------------------------------------------------- layer 2 + log_softmax
// thread = one full row (all 64 cols) -> softmax entirely in registers.
__global__ __launch_bounds__(256) void k_l2(
    const float* __restrict__ Hin, const float* __restrict__ AGG,
    const float* __restrict__ deg,
    const float* __restrict__ Wl, const float* __restrict__ Wr,
    const float* __restrict__ bias,
    float* __restrict__ OUT, int nRows)
{
  const int row = blockIdx.x * 256 + threadIdx.x;
  if (row >= nRows) return;
  const float invd = 1.0f / fmaxf(deg[row], 1.0f);

  float acc[OUT_C];
#pragma unroll
  for (int c = 0; c < OUT_C; ++c) acc[c] = 0.0f;

  const float* arow = AGG + (size_t)row * HID_C;
  const float* hrow = Hin + (size_t)row * HID_C;

#pragma unroll 1
  for (int kc = 0; kc < HID_C; kc += 16) {
    float a[16];
    const float4* p4 = (const float4*)(arow + kc);
#pragma unroll
    for (int i = 0; i < 4; ++i) {
      float4 t = p4[i];
      a[4*i+0] = t.x * invd; a[4*i+1] = t.y * invd;
      a[4*i+2] = t.z * invd; a[4*i+3] = t.w * invd;
    }
#pragma unroll
    for (int k = 0; k < 16; ++k)
#pragma unroll
      for (int c = 0; c < OUT_C; ++c)
        acc[c] = fmaf(a[k], Wl[c * HID_C + kc + k], acc[c]);
  }

#pragma unroll 1
  for (int kc = 0; kc < HID_C; kc += 16) {
    float a[16];
    const float4* p4 = (const float4*)(hrow + kc);
#pragma unroll
    for (int i = 0; i < 4; ++i) {
      float4 t = p4[i];
      a[4*i+0] = t.x; a[4*i+1] = t.y; a[4*i+2] = t.z; a[4*i+3] = t.w;
    }
#pragma unroll
    for (int k = 0; k < 16; ++k)
#pragma unroll
      for (int c = 0; c < OUT_C; ++c)
        acc[c] = fmaf(a[k], Wr[c * HID_C + kc + k], acc[c]);
  }

#pragma unroll
  for (int c = 0; c < OUT_C; ++c) acc[c] += bias[c];

  float m = acc[0];
#pragma unroll
  for (int c = 1; c < OUT_C; ++c) m = fmaxf(m, acc[c]);
  float s = 0.0f;
#pragma unroll
  for (int c = 0; c < OUT_C; ++c) s += __expf(acc[c] - m);
  const float lse = m + __logf(s);

  float* orow = OUT + (size_t)row * OUT_C;
#pragma unroll
  for (int i = 0; i < OUT_C / 4; ++i) {
    float4 o;
    o.x = acc[4*i+0] - lse; o.y = acc[4*i+1] - lse;
    o.z = acc[4*i+2] - lse; o.w = acc[4*i+3] - lse;
    ((float4*)orow)[i] = o;
  }
}

// ----------------------------------------------------------------- launch
extern "C" void kernel_launch(void* const* d_in, const int* in_sizes, int n_in,
                              void* d_out, int out_size, void* d_ws, size_t ws_size,
                              hipStream_t stream) {
  const float* x   = (const float*)d_in[0];
  const int*   ei  = (const int*)d_in[1];
  const float* W1l = (const float*)d_in[2];
  const float* W1r = (const float*)d_in[3];
  const float* b1  = (const float*)d_in[4];
  const float* W2l = (const float*)d_in[5];
  const float* W2r = (const float*)d_in[6];
  const float* b2  = (const float*)d_in[7];
  float* out = (float*)d_out;

  const int N  = in_sizes[0] / IN_C;      // 50000
  const int nE = in_sizes[1] / 2;         // 800000
  const int* src = ei;
  const int* dst = ei + nE;

  char* w = (char*)d_ws;
  float* deg = (float*)w;                                   // N floats
  float* agg = (float*)(w + 262144);                        // N*128 floats (reused by both layers)
  float* h   = (float*)(w + 262144 + (size_t)N * 128 * 4);  // N*128 floats

  hipMemsetAsync(deg, 0, (size_t)N * 4, stream);
  hipMemsetAsync(agg, 0, (size_t)N * 128 * 4, stream);

  k_deg<<<(nE + 255) / 256, 256, 0, stream>>>(dst, deg, nE);
  k_scatter<<<(nE + 3) / 4, 256, 0, stream>>>(x, src, dst, agg, nE);
  k_l1<<<(N + 63) / 64, 256, 0, stream>>>(x, agg, deg, W1l, W1r, b1, h, N);

  hipMemsetAsync(agg, 0, (size_t)N * 128 * 4, stream);
  k_scatter<<<(nE + 3) / 4, 256, 0, stream>>>(h, src, dst, agg, nE);
  k_l2<<<(N + 255) / 256, 256, 0, stream>>>(h, agg, deg, W2l, W2r, b2, out, N);
}

// Round 2
// 695.596 us; speedup vs baseline: 2.6517x; 2.6517x over previous
//
#include <hip/hip_runtime.h>
#include <hip/hip_bf16.h>

#define IN_C  128
#define HID_C 128
#define OUT_C 64
#define SCAN_BLK 256

// ------------------------------------------------------------ degree count
__global__ __launch_bounds__(256) void k_count(const int* __restrict__ dst,
                                               int* __restrict__ cnt, int nE) {
  int e = blockIdx.x * 256 + threadIdx.x;
  if (e < nE) atomicAdd(&cnt[dst[e]], 1);
}

// ------------------------------------------------------------ scan step 1
// per-block inclusive scan of cnt -> row_off[i] (local incl), partial[b] = block sum
__global__ __launch_bounds__(SCAN_BLK) void k_scan1(const int* __restrict__ cnt,
                                                    int* __restrict__ row_off,
                                                    int* __restrict__ partial, int n) {
  __shared__ int sh[SCAN_BLK];
  int t = threadIdx.x;
  int i = blockIdx.x * SCAN_BLK + t;
  int v = (i < n) ? cnt[i] : 0;
  sh[t] = v;
  __syncthreads();
#pragma unroll
  for (int o = 1; o < SCAN_BLK; o <<= 1) {
    int u = (t >= o) ? sh[t - o] : 0;
    __syncthreads();
    sh[t] += u;
    __syncthreads();
  }
  if (i < n) row_off[i] = sh[t];
  if (t == SCAN_BLK - 1) partial[blockIdx.x] = sh[t];
}

// ------------------------------------------------------------ scan step 2
// single block: exclusive scan of partials (in place)
__global__ __launch_bounds__(SCAN_BLK) void k_scan2(int* __restrict__ partial, int nb) {
  __shared__ int sh[SCAN_BLK];
  int t = threadIdx.x;
  int v = (t < nb) ? partial[t] : 0;
  sh[t] = v;
  __syncthreads();
#pragma unroll
  for (int o = 1; o < SCAN_BLK; o <<= 1) {
    int u = (t >= o) ? sh[t - o] : 0;
    __syncthreads();
    sh[t] += u;
    __syncthreads();
  }
  if (t < nb) partial[t] = sh[t] - v;   // exclusive
}

// ------------------------------------------------------------ scan step 3
// row_off[i] = global exclusive offset; cursor[i] = same (fill cursor);
// last element writes row_off[n] = total
__global__ __launch_bounds__(SCAN_BLK) void k_scan3(int* __restrict__ row_off,
                                                    int* __restrict__ cnt_cursor,
                                                    const int* __restrict__ partial, int n) {
  int i = blockIdx.x * SCAN_BLK + threadIdx.x;
  if (i >= n) return;
  int off = partial[blockIdx.x];
  int incl = row_off[i] + off;
  int excl = incl - cnt_cursor[i];
  row_off[i] = excl;
  cnt_cursor[i] = excl;          // becomes the fill cursor
  if (i == n - 1) row_off[n] = incl;
}

// ------------------------------------------------------------ CSR fill
__global__ __launch_bounds__(256) void k_fill(const int* __restrict__ src,
                                              const int* __restrict__ dst,
                                              int* __restrict__ cursor,
                                              int* __restrict__ csr, int nE) {
  int e = blockIdx.x * 256 + threadIdx.x;
  if (e < nE) {
    int pos = atomicAdd(&cursor[dst[e]], 1);
    csr[pos] = src[e];
  }
}

// ------------------------------------------------------------ gather + mean
// one wave per node; lane holds 2 channels; src indices are wave-uniform
__global__ __launch_bounds__(256) void k_gather(const float* __restrict__ X,
                                                const int* __restrict__ row_off,
                                                const int* __restrict__ csr,
                                                float* __restrict__ agg, int n) {
  const int lane = threadIdx.x & 63;
  const int node = blockIdx.x * 4 + __builtin_amdgcn_readfirstlane(threadIdx.x >> 6);
  if (node >= n) return;
  const int rs = row_off[node];
  const int re = row_off[node + 1];
  const float2* Xp = (const float2*)X;
  float ax = 0.0f, ay = 0.0f;
  int e = rs;
  for (; e + 4 <= re; e += 4) {
    int s0 = csr[e + 0], s1 = csr[e + 1], s2 = csr[e + 2], s3 = csr[e + 3];
    float2 a = Xp[(size_t)s0 * 64 + lane];
    float2 b = Xp[(size_t)s1 * 64 + lane];
    float2 c = Xp[(size_t)s2 * 64 + lane];
    float2 d = Xp[(size_t)s3 * 64 + lane];
    ax += a.x + b.x + c.x + d.x;
    ay += a.y + b.y + c.y + d.y;
  }
  for (; e < re; ++e) {
    int s = csr[e];
    float2 a = Xp[(size_t)s * 64 + lane];
    ax += a.x;
    ay += a.y;
  }
  const float invd = 1.0f / fmaxf((float)(re - rs), 1.0f);
  float2 o; o.x = ax * invd; o.y = ay * invd;
  ((float2*)agg)[(size_t)node * 64 + lane] = o;
}

// ------------------------------------------------------------- layer 1
// h = relu(aggmean @ Wl^T + x @ Wr^T + b)
__global__ __launch_bounds__(256) void k_l1(
    const float* __restrict__ X, const float* __restrict__ AGG,
    const float* __restrict__ Wl, const float* __restrict__ Wr,
    const float* __restrict__ bias,
    float* __restrict__ H, int nRows)
{
  const int lane = threadIdx.x & 63;
  const int c0 = __builtin_amdgcn_readfirstlane(threadIdx.x >> 6) * 32;
  const int row = blockIdx.x * 64 + lane;
  const bool active = row < nRows;
  const int r = active ? row : 0;

  float acc[32];
#pragma unroll
  for (int c = 0; c < 32; ++c) acc[c] = 0.0f;

  const float* arow = AGG + (size_t)r * IN_C;
  const float* xrow = X   + (size_t)r * IN_C;

#pragma unroll 1
  for (int kc = 0; kc < IN_C; kc += 16) {
    float a[16];
    const float4* p4 = (const float4*)(arow + kc);
#pragma unroll
    for (int i = 0; i < 4; ++i) {
      float4 t = p4[i];
      a[4*i+0] = t.x; a[4*i+1] = t.y; a[4*i+2] = t.z; a[4*i+3] = t.w;
    }
#pragma unroll
    for (int k = 0; k < 16; ++k)
#pragma unroll
      for (int c = 0; c < 32; ++c)
        acc[c] = fmaf(a[k], Wl[(c0 + c) * IN_C + kc + k], acc[c]);
  }

#pragma unroll 1
  for (int kc = 0; kc < IN_C; kc += 16) {
    float a[16];
    const float4* p4 = (const float4*)(xrow + kc);
#pragma unroll
    for (int i = 0; i < 4; ++i) {
      float4 t = p4[i];
      a[4*i+0] = t.x; a[4*i+1] = t.y; a[4*i+2] = t.z; a[4*i+3] = t.w;
    }
#pragma unroll
    for (int k = 0; k < 16; ++k)
#pragma unroll
      for (int c = 0; c < 32; ++c)
        acc[c] = fmaf(a[k], Wr[(c0 + c) * IN_C + kc + k], acc[c]);
  }

  if (active) {
    float* hrow = H + (size_t)row * HID_C + c0;
#pragma unroll
    for (int i = 0; i < 8; ++i) {
      float4 o;
      o.x = fmaxf(acc[4*i+0] + bias[c0+4*i+0], 0.0f);
      o.y = fmaxf(acc[4*i+1] + bias[c0+4*i+1], 0.0f);
      o.z = fmaxf(acc[4*i+2] + bias[c0+4*i+2], 0.0f);
      o.w = fmaxf(acc[4*i+3] + bias[c0+4*i+3], 0.0f);
      ((float4*)hrow)[i] = o;
    }
  }
}

// ------------------------------------------------- layer 2 + log_softmax
__global__ __launch_bounds__(256) void k_l2(
    const float* __restrict__ Hin, const float* __restrict__ AGG,
    const float* __restrict__ Wl, const float* __restrict__ Wr,
    const float* __restrict__ bias,
    float* __restrict__ OUT, int nRows)
{
  const int row = blockIdx.x * 256 + threadIdx.x;
  if (row >= nRows) return;

  float acc[OUT_C];
#pragma unroll
  for (int c = 0; c < OUT_C; ++c) acc[c] = 0.0f;

  const float* arow = AGG + (size_t)row * HID_C;
  const float* hrow = Hin + (size_t)row * HID_C;

#pragma unroll 1
  for (int kc = 0; kc < HID_C; kc += 16) {
    float a[16];
    const float4* p4 = (const float4*)(arow + kc);
#pragma unroll
    for (int i = 0; i < 4; ++i) {
      float4 t = p4[i];
      a[4*i+0] = t.x; a[4*i+1] = t.y; a[4*i+2] = t.z; a[4*i+3] = t.w;
    }
#pragma unroll
    for (int k = 0; k < 16; ++k)
#pragma unroll
      for (int c = 0; c < OUT_C; ++c)
        acc[c] = fmaf(a[k], Wl[c * HID_C + kc + k], acc[c]);
  }

#pragma unroll 1
  for (int kc = 0; kc < HID_C; kc += 16) {
    float a[16];
    const float4* p4 = (const float4*)(hrow + kc);
#pragma unroll
    for (int i = 0; i < 4; ++i) {
      float4 t = p4[i];
      a[4*i+0] = t.x; a[4*i+1] = t.y; a[4*i+2] = t.z; a[4*i+3] = t.w;
    }
#pragma unroll
    for (int k = 0; k < 16; ++k)
#pragma unroll
      for (int c = 0; c < OUT_C; ++c)
        acc[c] = fmaf(a[k], Wr[c * HID_C + kc + k], acc[c]);
  }

#pragma unroll
  for (int c = 0; c < OUT_C; ++c) acc[c] += bias[c];

  float m = acc[0];
#pragma unroll
  for (int c = 1; c < OUT_C; ++c) m = fmaxf(m, acc[c]);
  float s = 0.0f;
#pragma unroll
  for (int c = 0; c < OUT_C; ++c) s += __expf(acc[c] - m);
  const float lse = m + __logf(s);

  float* orow = OUT + (size_t)row * OUT_C;
#pragma unroll
  for (int i = 0; i < OUT_C / 4; ++i) {
    float4 o;
    o.x = acc[4*i+0] - lse; o.y = acc[4*i+1] - lse;
    o.z = acc[4*i+2] - lse; o.w = acc[4*i+3] - lse;
    ((float4*)orow)[i] = o;
  }
}

// ----------------------------------------------------------------- launch
extern "C" void kernel_launch(void* const* d_in, const int* in_sizes, int n_in,
                              void* d_out, int out_size, void* d_ws, size_t ws_size,
                              hipStream_t stream) {
  const float* x   = (const float*)d_in[0];
  const int*   ei  = (const int*)d_in[1];
  const float* W1l = (const float*)d_in[2];
  const float* W1r = (const float*)d_in[3];
  const float* b1  = (const float*)d_in[4];
  const float* W2l = (const float*)d_in[5];
  const float* W2r = (const float*)d_in[6];
  const float* b2  = (const float*)d_in[7];
  float* out = (float*)d_out;

  const int N  = in_sizes[0] / IN_C;      // 50000
  const int nE = in_sizes[1] / 2;         // 800000
  const int* src = ei;
  const int* dst = ei + nE;

  const int NB = (N + SCAN_BLK - 1) / SCAN_BLK;   // 196

  char* w = (char*)d_ws;
  size_t off = 0;
  int* row_off = (int*)(w + off); off += ((size_t)(N + 1) * 4 + 255) & ~255ull;
  int* cnt     = (int*)(w + off); off += ((size_t)N * 4 + 255) & ~255ull;       // count, then cursor
  int* partial = (int*)(w + off); off += 1024;
  int* csr     = (int*)(w + off); off += (size_t)nE * 4;
  float* agg   = (float*)(w + off); off += (size_t)N * 128 * 4;
  float* h     = (float*)(w + off); off += (size_t)N * 128 * 4;

  hipMemsetAsync(cnt, 0, (size_t)N * 4, stream);

  // --- build CSR (dst-bucketed src lists) ---
  k_count<<<(nE + 255) / 256, 256, 0, stream>>>(dst, cnt, nE);
  k_scan1<<<NB, SCAN_BLK, 0, stream>>>(cnt, row_off, partial, N);
  k_scan2<<<1, SCAN_BLK, 0, stream>>>(partial, NB);
  k_scan3<<<NB, SCAN_BLK, 0, stream>>>(row_off, cnt, partial, N);
  k_fill<<<(nE + 255) / 256, 256, 0, stream>>>(src, dst, cnt, csr, nE);

  // --- layer 1 ---
  k_gather<<<(N + 3) / 4, 256, 0, stream>>>(x, row_off, csr, agg, N);
  k_l1<<<(N + 63) / 64, 256, 0, stream>>>(x, agg, W1l, W1r, b1, h, N);

  // --- layer 2 ---
  k_gather<<<(N + 3) / 4, 256, 0, stream>>>(h, row_off, csr, agg, N);
  k_l2<<<(N + 255) / 256, 256, 0, stream>>>(h, agg, W2l, W2r, b2, out, N);
}

// Round 3
// 693.736 us; speedup vs baseline: 2.6588x; 1.0027x over previous
//
#include <hip/hip_runtime.h>
#include <hip/hip_bf16.h>

#define IN_C  128
#define HID_C 128
#define OUT_C 64
#define SCAN_BLK 256

// ------------------------------------------------------------ degree count
__global__ __launch_bounds__(256) void k_count(const int* __restrict__ dst,
                                               int* __restrict__ cnt, int nE) {
  int e = blockIdx.x * 256 + threadIdx.x;
  if (e < nE) atomicAdd(&cnt[dst[e]], 1);
}

// ------------------------------------------------------------ scan step 1
__global__ __launch_bounds__(SCAN_BLK) void k_scan1(const int* __restrict__ cnt,
                                                    int* __restrict__ row_off,
                                                    int* __restrict__ partial, int n) {
  __shared__ int sh[SCAN_BLK];
  int t = threadIdx.x;
  int i = blockIdx.x * SCAN_BLK + t;
  int v = (i < n) ? cnt[i] : 0;
  sh[t] = v;
  __syncthreads();
#pragma unroll
  for (int o = 1; o < SCAN_BLK; o <<= 1) {
    int u = (t >= o) ? sh[t - o] : 0;
    __syncthreads();
    sh[t] += u;
    __syncthreads();
  }
  if (i < n) row_off[i] = sh[t];
  if (t == SCAN_BLK - 1) partial[blockIdx.x] = sh[t];
}

// ------------------------------------------------------------ scan step 2
__global__ __launch_bounds__(SCAN_BLK) void k_scan2(int* __restrict__ partial, int nb) {
  __shared__ int sh[SCAN_BLK];
  int t = threadIdx.x;
  int v = (t < nb) ? partial[t] : 0;
  sh[t] = v;
  __syncthreads();
#pragma unroll
  for (int o = 1; o < SCAN_BLK; o <<= 1) {
    int u = (t >= o) ? sh[t - o] : 0;
    __syncthreads();
    sh[t] += u;
    __syncthreads();
  }
  if (t < nb) partial[t] = sh[t] - v;   // exclusive
}

// ------------------------------------------------------------ scan step 3
__global__ __launch_bounds__(SCAN_BLK) void k_scan3(int* __restrict__ row_off,
                                                    int* __restrict__ cnt_cursor,
                                                    const int* __restrict__ partial, int n) {
  int i = blockIdx.x * SCAN_BLK + threadIdx.x;
  if (i >= n) return;
  int off = partial[blockIdx.x];
  int incl = row_off[i] + off;
  int excl = incl - cnt_cursor[i];
  row_off[i] = excl;
  cnt_cursor[i] = excl;          // becomes the fill cursor
  if (i == n - 1) row_off[n] = incl;
}

// ------------------------------------------------------------ CSR fill
__global__ __launch_bounds__(256) void k_fill(const int* __restrict__ src,
                                              const int* __restrict__ dst,
                                              int* __restrict__ cursor,
                                              int* __restrict__ csr, int nE) {
  int e = blockIdx.x * 256 + threadIdx.x;
  if (e < nE) {
    int pos = atomicAdd(&cursor[dst[e]], 1);
    csr[pos] = src[e];
  }
}

// ------------------------------------------------------------ gather + mean
// one wave per node; lane holds 2 channels; src indices are wave-uniform
__global__ __launch_bounds__(256, 2) void k_gather(const float* __restrict__ X,
                                                   const int* __restrict__ row_off,
                                                   const int* __restrict__ csr,
                                                   float* __restrict__ agg, int n) {
  const int lane = threadIdx.x & 63;
  const int node = blockIdx.x * 4 + __builtin_amdgcn_readfirstlane(threadIdx.x >> 6);
  if (node >= n) return;
  const int rs = row_off[node];
  const int re = row_off[node + 1];
  const float2* Xp = (const float2*)X;
  float ax = 0.0f, ay = 0.0f;
  int e = rs;
  for (; e + 4 <= re; e += 4) {
    int s0 = csr[e + 0], s1 = csr[e + 1], s2 = csr[e + 2], s3 = csr[e + 3];
    float2 a = Xp[(size_t)s0 * 64 + lane];
    float2 b = Xp[(size_t)s1 * 64 + lane];
    float2 c = Xp[(size_t)s2 * 64 + lane];
    float2 d = Xp[(size_t)s3 * 64 + lane];
    ax += a.x + b.x + c.x + d.x;
    ay += a.y + b.y + c.y + d.y;
  }
  for (; e < re; ++e) {
    int s = csr[e];
    float2 a = Xp[(size_t)s * 64 + lane];
    ax += a.x;
    ay += a.y;
  }
  const float invd = 1.0f / fmaxf((float)(re - rs), 1.0f);
  float2 o; o.x = ax * invd; o.y = ay * invd;
  ((float2*)agg)[(size_t)node * 64 + lane] = o;
}

// ------------------------------------------------------------- layer 1
// h = relu(aggmean @ Wl^T + x @ Wr^T + b)
// thread = row; wave = 64 rows; 4 waves/block each own a 32-col chunk.
// __launch_bounds__(256,2): VGPR cap 256 -> no accumulator spill (needs ~70).
__global__ __launch_bounds__(256, 2) void k_l1(
    const float* __restrict__ X, const float* __restrict__ AGG,
    const float* __restrict__ Wl, const float* __restrict__ Wr,
    const float* __restrict__ bias,
    float* __restrict__ H, int nRows)
{
  const int lane = threadIdx.x & 63;
  const int c0 = __builtin_amdgcn_readfirstlane(threadIdx.x >> 6) * 32;
  const int row = blockIdx.x * 64 + lane;
  const bool active = row < nRows;
  const int r = active ? row : 0;

  float acc[32];
#pragma unroll
  for (int c = 0; c < 32; ++c) acc[c] = 0.0f;

  const float* arow = AGG + (size_t)r * IN_C;
  const float* xrow = X   + (size_t)r * IN_C;

#pragma unroll 1
  for (int kc = 0; kc < IN_C; kc += 16) {
    float a[16];
    const float4* p4 = (const float4*)(arow + kc);
#pragma unroll
    for (int i = 0; i < 4; ++i) {
      float4 t = p4[i];
      a[4*i+0] = t.x; a[4*i+1] = t.y; a[4*i+2] = t.z; a[4*i+3] = t.w;
    }
#pragma unroll
    for (int k = 0; k < 16; ++k)
#pragma unroll
      for (int c = 0; c < 32; ++c)
        acc[c] = fmaf(a[k], Wl[(c0 + c) * IN_C + kc + k], acc[c]);
  }

#pragma unroll 1
  for (int kc = 0; kc < IN_C; kc += 16) {
    float a[16];
    const float4* p4 = (const float4*)(xrow + kc);
#pragma unroll
    for (int i = 0; i < 4; ++i) {
      float4 t = p4[i];
      a[4*i+0] = t.x; a[4*i+1] = t.y; a[4*i+2] = t.z; a[4*i+3] = t.w;
    }
#pragma unroll
    for (int k = 0; k < 16; ++k)
#pragma unroll
      for (int c = 0; c < 32; ++c)
        acc[c] = fmaf(a[k], Wr[(c0 + c) * IN_C + kc + k], acc[c]);
  }

  if (active) {
    float* hrow = H + (size_t)row * HID_C + c0;
#pragma unroll
    for (int i = 0; i < 8; ++i) {
      float4 o;
      o.x = fmaxf(acc[4*i+0] + bias[c0+4*i+0], 0.0f);
      o.y = fmaxf(acc[4*i+1] + bias[c0+4*i+1], 0.0f);
      o.z = fmaxf(acc[4*i+2] + bias[c0+4*i+2], 0.0f);
      o.w = fmaxf(acc[4*i+3] + bias[c0+4*i+3], 0.0f);
      ((float4*)hrow)[i] = o;
    }
  }
}

// ------------------------------------------------- layer 2 + log_softmax
// thread = full row (64 cols, in-register softmax). One wave per block ->
// grid 782 covers all 256 CUs. __launch_bounds__(64,1): no VGPR cap spill
// (needs ~100 regs for acc[64]+a[16]).
__global__ __launch_bounds__(64, 1) void k_l2(
    const float* __restrict__ Hin, const float* __restrict__ AGG,
    const float* __restrict__ Wl, const float* __restrict__ Wr,
    const float* __restrict__ bias,
    float* __restrict__ OUT, int nRows)
{
  const int row = blockIdx.x * 64 + threadIdx.x;
  if (row >= nRows) return;

  float acc[OUT_C];
#pragma unroll
  for (int c = 0; c < OUT_C; ++c) acc[c] = 0.0f;

  const float* arow = AGG + (size_t)row * HID_C;
  const float* hrow = Hin + (size_t)row * HID_C;

#pragma unroll 1
  for (int kc = 0; kc < HID_C; kc += 16) {
    float a[16];
    const float4* p4 = (const float4*)(arow + kc);
#pragma unroll
    for (int i = 0; i < 4; ++i) {
      float4 t = p4[i];
      a[4*i+0] = t.x; a[4*i+1] = t.y; a[4*i+2] = t.z; a[4*i+3] = t.w;
    }
#pragma unroll
    for (int k = 0; k < 16; ++k)
#pragma unroll
      for (int c = 0; c < OUT_C; ++c)
        acc[c] = fmaf(a[k], Wl[c * HID_C + kc + k], acc[c]);
  }

#pragma unroll 1
  for (int kc = 0; kc < HID_C; kc += 16) {
    float a[16];
    const float4* p4 = (const float4*)(hrow + kc);
#pragma unroll
    for (int i = 0; i < 4; ++i) {
      float4 t = p4[i];
      a[4*i+0] = t.x; a[4*i+1] = t.y; a[4*i+2] = t.z; a[4*i+3] = t.w;
    }
#pragma unroll
    for (int k = 0; k < 16; ++k)
#pragma unroll
      for (int c = 0; c < OUT_C; ++c)
        acc[c] = fmaf(a[k], Wr[c * HID_C + kc + k], acc[c]);
  }

#pragma unroll
  for (int c = 0; c < OUT_C; ++c) acc[c] += bias[c];

  float m = acc[0];
#pragma unroll
  for (int c = 1; c < OUT_C; ++c) m = fmaxf(m, acc[c]);
  float s = 0.0f;
#pragma unroll
  for (int c = 0; c < OUT_C; ++c) s += __expf(acc[c] - m);
  const float lse = m + __logf(s);

  float* orow = OUT + (size_t)row * OUT_C;
#pragma unroll
  for (int i = 0; i < OUT_C / 4; ++i) {
    float4 o;
    o.x = acc[4*i+0] - lse; o.y = acc[4*i+1] - lse;
    o.z = acc[4*i+2] - lse; o.w = acc[4*i+3] - lse;
    ((float4*)orow)[i] = o;
  }
}

// ----------------------------------------------------------------- launch
extern "C" void kernel_launch(void* const* d_in, const int* in_sizes, int n_in,
                              void* d_out, int out_size, void* d_ws, size_t ws_size,
                              hipStream_t stream) {
  const float* x   = (const float*)d_in[0];
  const int*   ei  = (const int*)d_in[1];
  const float* W1l = (const float*)d_in[2];
  const float* W1r = (const float*)d_in[3];
  const float* b1  = (const float*)d_in[4];
  const float* W2l = (const float*)d_in[5];
  const float* W2r = (const float*)d_in[6];
  const float* b2  = (const float*)d_in[7];
  float* out = (float*)d_out;

  const int N  = in_sizes[0] / IN_C;      // 50000
  const int nE = in_sizes[1] / 2;         // 800000
  const int* src = ei;
  const int* dst = ei + nE;

  const int NB = (N + SCAN_BLK - 1) / SCAN_BLK;   // 196

  char* w = (char*)d_ws;
  size_t off = 0;
  int* row_off = (int*)(w + off); off += ((size_t)(N + 1) * 4 + 255) & ~255ull;
  int* cnt     = (int*)(w + off); off += ((size_t)N * 4 + 255) & ~255ull;       // count, then cursor
  int* partial = (int*)(w + off); off += 1024;
  int* csr     = (int*)(w + off); off += (size_t)nE * 4;
  float* agg   = (float*)(w + off); off += (size_t)N * 128 * 4;
  float* h     = (float*)(w + off); off += (size_t)N * 128 * 4;

  hipMemsetAsync(cnt, 0, (size_t)N * 4, stream);

  // --- build CSR (dst-bucketed src lists) ---
  k_count<<<(nE + 255) / 256, 256, 0, stream>>>(dst, cnt, nE);
  k_scan1<<<NB, SCAN_BLK, 0, stream>>>(cnt, row_off, partial, N);
  k_scan2<<<1, SCAN_BLK, 0, stream>>>(partial, NB);
  k_scan3<<<NB, SCAN_BLK, 0, stream>>>(row_off, cnt, partial, N);
  k_fill<<<(nE + 255) / 256, 256, 0, stream>>>(src, dst, cnt, csr, nE);

  // --- layer 1 ---
  k_gather<<<(N + 3) / 4, 256, 0, stream>>>(x, row_off, csr, agg, N);
  k_l1<<<(N + 63) / 64, 256, 0, stream>>>(x, agg, W1l, W1r, b1, h, N);

  // --- layer 2 ---
  k_gather<<<(N + 3) / 4, 256, 0, stream>>>(h, row_off, csr, agg, N);
  k_l2<<<(N + 63) / 64, 64, 0, stream>>>(h, agg, W2l, W2r, b2, out, N);
}

// Round 4
// 423.992 us; speedup vs baseline: 4.3503x; 1.6362x over previous
//
#include <hip/hip_runtime.h>
#include <hip/hip_bf16.h>

#define IN_C  128
#define HID_C 128
#define OUT_C 64
#define SCAN_BLK 256

// ------------------------------------------------------------ degree count
__global__ __launch_bounds__(256) void k_count(const int* __restrict__ dst,
                                               int* __restrict__ cnt, int nE) {
  int e = blockIdx.x * 256 + threadIdx.x;
  if (e < nE) atomicAdd(&cnt[dst[e]], 1);
}

// ------------------------------------------------------------ scan step 1
__global__ __launch_bounds__(SCAN_BLK) void k_scan1(const int* __restrict__ cnt,
                                                    int* __restrict__ row_off,
                                                    int* __restrict__ partial, int n) {
  __shared__ int sh[SCAN_BLK];
  int t = threadIdx.x;
  int i = blockIdx.x * SCAN_BLK + t;
  int v = (i < n) ? cnt[i] : 0;
  sh[t] = v;
  __syncthreads();
#pragma unroll
  for (int o = 1; o < SCAN_BLK; o <<= 1) {
    int u = (t >= o) ? sh[t - o] : 0;
    __syncthreads();
    sh[t] += u;
    __syncthreads();
  }
  if (i < n) row_off[i] = sh[t];
  if (t == SCAN_BLK - 1) partial[blockIdx.x] = sh[t];
}

// ------------------------------------------------------------ scan step 2
__global__ __launch_bounds__(SCAN_BLK) void k_scan2(int* __restrict__ partial, int nb) {
  __shared__ int sh[SCAN_BLK];
  int t = threadIdx.x;
  int v = (t < nb) ? partial[t] : 0;
  sh[t] = v;
  __syncthreads();
#pragma unroll
  for (int o = 1; o < SCAN_BLK; o <<= 1) {
    int u = (t >= o) ? sh[t - o] : 0;
    __syncthreads();
    sh[t] += u;
    __syncthreads();
  }
  if (t < nb) partial[t] = sh[t] - v;   // exclusive
}

// ------------------------------------------------------------ scan step 3
__global__ __launch_bounds__(SCAN_BLK) void k_scan3(int* __restrict__ row_off,
                                                    int* __restrict__ cnt_cursor,
                                                    const int* __restrict__ partial, int n) {
  int i = blockIdx.x * SCAN_BLK + threadIdx.x;
  if (i >= n) return;
  int off = partial[blockIdx.x];
  int incl = row_off[i] + off;
  int excl = incl - cnt_cursor[i];
  row_off[i] = excl;
  cnt_cursor[i] = excl;          // becomes the fill cursor
  if (i == n - 1) row_off[n] = incl;
}

// ------------------------------------------------------------ CSR fill
__global__ __launch_bounds__(256) void k_fill(const int* __restrict__ src,
                                              const int* __restrict__ dst,
                                              int* __restrict__ cursor,
                                              int* __restrict__ csr, int nE) {
  int e = blockIdx.x * 256 + threadIdx.x;
  if (e < nE) {
    int pos = atomicAdd(&cursor[dst[e]], 1);
    csr[pos] = src[e];
  }
}

// ------------------------------------------------------------ gather + mean
// one wave per node; lane holds 2 channels; src indices are wave-uniform
__global__ __launch_bounds__(256, 2) void k_gather(const float* __restrict__ X,
                                                   const int* __restrict__ row_off,
                                                   const int* __restrict__ csr,
                                                   float* __restrict__ agg, int n) {
  const int lane = threadIdx.x & 63;
  const int node = blockIdx.x * 4 + __builtin_amdgcn_readfirstlane(threadIdx.x >> 6);
  if (node >= n) return;
  const int rs = row_off[node];
  const int re = row_off[node + 1];
  const float2* Xp = (const float2*)X;
  float ax = 0.0f, ay = 0.0f;
  int e = rs;
  for (; e + 4 <= re; e += 4) {
    int s0 = csr[e + 0], s1 = csr[e + 1], s2 = csr[e + 2], s3 = csr[e + 3];
    float2 a = Xp[(size_t)s0 * 64 + lane];
    float2 b = Xp[(size_t)s1 * 64 + lane];
    float2 c = Xp[(size_t)s2 * 64 + lane];
    float2 d = Xp[(size_t)s3 * 64 + lane];
    ax += a.x + b.x + c.x + d.x;
    ay += a.y + b.y + c.y + d.y;
  }
  for (; e < re; ++e) {
    int s = csr[e];
    float2 a = Xp[(size_t)s * 64 + lane];
    ax += a.x;
    ay += a.y;
  }
  const float invd = 1.0f / fmaxf((float)(re - rs), 1.0f);
  float2 o; o.x = ax * invd; o.y = ay * invd;
  ((float2*)agg)[(size_t)node * 64 + lane] = o;
}

// ------------------------------------------------------------- layer 1
// h = relu(aggmean @ Wl^T + x @ Wr^T + b)
// lane = row (64 rows/block), wave = 32-col chunk (4 waves = 128 cols).
// live set: acc[32] + a[8] + addr ~= 50 VGPR -> no spill even at a 64 cap.
__global__ __launch_bounds__(256, 4) void k_l1(
    const float* __restrict__ X, const float* __restrict__ AGG,
    const float* __restrict__ Wl, const float* __restrict__ Wr,
    const float* __restrict__ bias,
    float* __restrict__ H, int nRows)
{
  const int lane = threadIdx.x & 63;
  const int c0 = __builtin_amdgcn_readfirstlane(threadIdx.x >> 6) * 32;
  const int row = blockIdx.x * 64 + lane;
  const bool active = row < nRows;
  const int r = active ? row : 0;

  float acc[32];
#pragma unroll
  for (int c = 0; c < 32; ++c) acc[c] = 0.0f;

  const float* arow = AGG + (size_t)r * IN_C;
  const float* xrow = X   + (size_t)r * IN_C;

#pragma unroll 1
  for (int kc = 0; kc < IN_C; kc += 8) {
    float4 t0 = ((const float4*)(arow + kc))[0];
    float4 t1 = ((const float4*)(arow + kc))[1];
    float a[8] = {t0.x, t0.y, t0.z, t0.w, t1.x, t1.y, t1.z, t1.w};
#pragma unroll
    for (int k = 0; k < 8; ++k)
#pragma unroll
      for (int c = 0; c < 32; ++c)
        acc[c] = fmaf(a[k], Wl[(c0 + c) * IN_C + kc + k], acc[c]);
  }

#pragma unroll 1
  for (int kc = 0; kc < IN_C; kc += 8) {
    float4 t0 = ((const float4*)(xrow + kc))[0];
    float4 t1 = ((const float4*)(xrow + kc))[1];
    float a[8] = {t0.x, t0.y, t0.z, t0.w, t1.x, t1.y, t1.z, t1.w};
#pragma unroll
    for (int k = 0; k < 8; ++k)
#pragma unroll
      for (int c = 0; c < 32; ++c)
        acc[c] = fmaf(a[k], Wr[(c0 + c) * IN_C + kc + k], acc[c]);
  }

  if (active) {
    float* hrow = H + (size_t)row * HID_C + c0;
#pragma unroll
    for (int i = 0; i < 8; ++i) {
      float4 o;
      o.x = fmaxf(acc[4*i+0] + bias[c0+4*i+0], 0.0f);
      o.y = fmaxf(acc[4*i+1] + bias[c0+4*i+1], 0.0f);
      o.z = fmaxf(acc[4*i+2] + bias[c0+4*i+2], 0.0f);
      o.w = fmaxf(acc[4*i+3] + bias[c0+4*i+3], 0.0f);
      ((float4*)hrow)[i] = o;
    }
  }
}

// ------------------------------------------------- layer 2 + log_softmax
// lane = row (64 rows/block), wave = 16-col chunk (4 waves = 64 cols).
// live set: acc[16] + a[8] ~= 35 VGPR. softmax max/sum combined across
// the 4 waves via LDS (each lane owns one row's partial).
__global__ __launch_bounds__(256, 4) void k_l2(
    const float* __restrict__ Hin, const float* __restrict__ AGG,
    const float* __restrict__ Wl, const float* __restrict__ Wr,
    const float* __restrict__ bias,
    float* __restrict__ OUT, int nRows)
{
  __shared__ float redm[4][64];
  __shared__ float reds[4][64];

  const int lane = threadIdx.x & 63;
  const int wid = __builtin_amdgcn_readfirstlane(threadIdx.x >> 6);
  const int c0 = wid * 16;
  const int row = blockIdx.x * 64 + lane;
  const bool active = row < nRows;
  const int r = active ? row : 0;

  float acc[16];
#pragma unroll
  for (int c = 0; c < 16; ++c) acc[c] = 0.0f;

  const float* arow = AGG + (size_t)r * HID_C;
  const float* hrow = Hin + (size_t)r * HID_C;

#pragma unroll 1
  for (int kc = 0; kc < HID_C; kc += 8) {
    float4 t0 = ((const float4*)(arow + kc))[0];
    float4 t1 = ((const float4*)(arow + kc))[1];
    float a[8] = {t0.x, t0.y, t0.z, t0.w, t1.x, t1.y, t1.z, t1.w};
#pragma unroll
    for (int k = 0; k < 8; ++k)
#pragma unroll
      for (int c = 0; c < 16; ++c)
        acc[c] = fmaf(a[k], Wl[(c0 + c) * HID_C + kc + k], acc[c]);
  }

#pragma unroll 1
  for (int kc = 0; kc < HID_C; kc += 8) {
    float4 t0 = ((const float4*)(hrow + kc))[0];
    float4 t1 = ((const float4*)(hrow + kc))[1];
    float a[8] = {t0.x, t0.y, t0.z, t0.w, t1.x, t1.y, t1.z, t1.w};
#pragma unroll
    for (int k = 0; k < 8; ++k)
#pragma unroll
      for (int c = 0; c < 16; ++c)
        acc[c] = fmaf(a[k], Wr[(c0 + c) * HID_C + kc + k], acc[c]);
  }

#pragma unroll
  for (int c = 0; c < 16; ++c) acc[c] += bias[c0 + c];

  // --- cross-wave log_softmax reduction (per row = per lane) ---
  float pm = acc[0];
#pragma unroll
  for (int c = 1; c < 16; ++c) pm = fmaxf(pm, acc[c]);
  redm[wid][lane] = pm;
  __syncthreads();
  const float m = fmaxf(fmaxf(redm[0][lane], redm[1][lane]),
                        fmaxf(redm[2][lane], redm[3][lane]));

  float s = 0.0f;
#pragma unroll
  for (int c = 0; c < 16; ++c) s += __expf(acc[c] - m);
  reds[wid][lane] = s;
  __syncthreads();
  const float tot = (reds[0][lane] + reds[1][lane]) + (reds[2][lane] + reds[3][lane]);
  const float lse = m + __logf(tot);

  if (active) {
    float* orow = OUT + (size_t)row * OUT_C + c0;
#pragma unroll
    for (int i = 0; i < 4; ++i) {
      float4 o;
      o.x = acc[4*i+0] - lse; o.y = acc[4*i+1] - lse;
      o.z = acc[4*i+2] - lse; o.w = acc[4*i+3] - lse;
      ((float4*)orow)[i] = o;
    }
  }
}

// ----------------------------------------------------------------- launch
extern "C" void kernel_launch(void* const* d_in, const int* in_sizes, int n_in,
                              void* d_out, int out_size, void* d_ws, size_t ws_size,
                              hipStream_t stream) {
  const float* x   = (const float*)d_in[0];
  const int*   ei  = (const int*)d_in[1];
  const float* W1l = (const float*)d_in[2];
  const float* W1r = (const float*)d_in[3];
  const float* b1  = (const float*)d_in[4];
  const float* W2l = (const float*)d_in[5];
  const float* W2r = (const float*)d_in[6];
  const float* b2  = (const float*)d_in[7];
  float* out = (float*)d_out;

  const int N  = in_sizes[0] / IN_C;      // 50000
  const int nE = in_sizes[1] / 2;         // 800000
  const int* src = ei;
  const int* dst = ei + nE;

  const int NB = (N + SCAN_BLK - 1) / SCAN_BLK;   // 196

  char* w = (char*)d_ws;
  size_t off = 0;
  int* row_off = (int*)(w + off); off += ((size_t)(N + 1) * 4 + 255) & ~255ull;
  int* cnt     = (int*)(w + off); off += ((size_t)N * 4 + 255) & ~255ull;       // count, then cursor
  int* partial = (int*)(w + off); off += 1024;
  int* csr     = (int*)(w + off); off += (size_t)nE * 4;
  float* agg   = (float*)(w + off); off += (size_t)N * 128 * 4;
  float* h     = (float*)(w + off); off += (size_t)N * 128 * 4;

  hipMemsetAsync(cnt, 0, (size_t)N * 4, stream);

  // --- build CSR (dst-bucketed src lists) ---
  k_count<<<(nE + 255) / 256, 256, 0, stream>>>(dst, cnt, nE);
  k_scan1<<<NB, SCAN_BLK, 0, stream>>>(cnt, row_off, partial, N);
  k_scan2<<<1, SCAN_BLK, 0, stream>>>(partial, NB);
  k_scan3<<<NB, SCAN_BLK, 0, stream>>>(row_off, cnt, partial, N);
  k_fill<<<(nE + 255) / 256, 256, 0, stream>>>(src, dst, cnt, csr, nE);

  // --- layer 1 ---
  k_gather<<<(N + 3) / 4, 256, 0, stream>>>(x, row_off, csr, agg, N);
  k_l1<<<(N + 63) / 64, 256, 0, stream>>>(x, agg, W1l, W1r, b1, h, N);

  // --- layer 2 ---
  k_gather<<<(N + 3) / 4, 256, 0, stream>>>(h, row_off, csr, agg, N);
  k_l2<<<(N + 63) / 64, 256, 0, stream>>>(h, agg, W2l, W2r, b2, out, N);
}

// Round 5
// 229.203 us; speedup vs baseline: 8.0475x; 1.8498x over previous
//
#include <hip/hip_runtime.h>
#include <hip/hip_bf16.h>

#define IN_C  128
#define HID_C 128
#define OUT_C 64
#define SCAN_BLK 256

typedef __attribute__((ext_vector_type(8))) short short8;
typedef __attribute__((ext_vector_type(4))) float f32x4;

__device__ __forceinline__ unsigned short f2bf(float f) {
  unsigned int u = __float_as_uint(f);
  unsigned int r = (u + 0x7fffu + ((u >> 16) & 1u)) >> 16;   // RNE
  return (unsigned short)r;
}
__device__ __forceinline__ float bflo(unsigned int v) { return __uint_as_float(v << 16); }
__device__ __forceinline__ float bfhi(unsigned int v) { return __uint_as_float(v & 0xffff0000u); }

// ------------------------------------------------------------ degree count
__global__ __launch_bounds__(256) void k_count(const int* __restrict__ dst,
                                               int* __restrict__ cnt, int nE) {
  int e = blockIdx.x * 256 + threadIdx.x;
  if (e < nE) atomicAdd(&cnt[dst[e]], 1);
}

// ------------------------------------------------------------ scan step 1
__global__ __launch_bounds__(SCAN_BLK) void k_scan1(const int* __restrict__ cnt,
                                                    int* __restrict__ row_off,
                                                    int* __restrict__ partial, int n) {
  __shared__ int sh[SCAN_BLK];
  int t = threadIdx.x;
  int i = blockIdx.x * SCAN_BLK + t;
  int v = (i < n) ? cnt[i] : 0;
  sh[t] = v;
  __syncthreads();
#pragma unroll
  for (int o = 1; o < SCAN_BLK; o <<= 1) {
    int u = (t >= o) ? sh[t - o] : 0;
    __syncthreads();
    sh[t] += u;
    __syncthreads();
  }
  if (i < n) row_off[i] = sh[t];
  if (t == SCAN_BLK - 1) partial[blockIdx.x] = sh[t];
}

// ------------------------------------------------------------ scan step 2
__global__ __launch_bounds__(SCAN_BLK) void k_scan2(int* __restrict__ partial, int nb) {
  __shared__ int sh[SCAN_BLK];
  int t = threadIdx.x;
  int v = (t < nb) ? partial[t] : 0;
  sh[t] = v;
  __syncthreads();
#pragma unroll
  for (int o = 1; o < SCAN_BLK; o <<= 1) {
    int u = (t >= o) ? sh[t - o] : 0;
    __syncthreads();
    sh[t] += u;
    __syncthreads();
  }
  if (t < nb) partial[t] = sh[t] - v;   // exclusive
}

// ------------------------------------------------------------ scan step 3
__global__ __launch_bounds__(SCAN_BLK) void k_scan3(int* __restrict__ row_off,
                                                    int* __restrict__ cnt_cursor,
                                                    const int* __restrict__ partial, int n) {
  int i = blockIdx.x * SCAN_BLK + threadIdx.x;
  if (i >= n) return;
  int off = partial[blockIdx.x];
  int incl = row_off[i] + off;
  int excl = incl - cnt_cursor[i];
  row_off[i] = excl;
  cnt_cursor[i] = excl;          // becomes the fill cursor
  if (i == n - 1) row_off[n] = incl;
}

// ------------------------------------------------------------ CSR fill
__global__ __launch_bounds__(256) void k_fill(const int* __restrict__ src,
                                              const int* __restrict__ dst,
                                              int* __restrict__ cursor,
                                              int* __restrict__ csr, int nE) {
  int e = blockIdx.x * 256 + threadIdx.x;
  if (e < nE) {
    int pos = atomicAdd(&cursor[dst[e]], 1);
    csr[pos] = src[e];
  }
}

// ------------------------------------------------------------ fp32 -> bf16 (x)
__global__ __launch_bounds__(256) void k_cvt_x(const float* __restrict__ X,
                                               unsigned short* __restrict__ Xb, int n4) {
  int i = blockIdx.x * 256 + threadIdx.x;
  if (i >= n4) return;
  float4 v = ((const float4*)X)[i];
  uint2 o;
  o.x = (unsigned int)f2bf(v.x) | ((unsigned int)f2bf(v.y) << 16);
  o.y = (unsigned int)f2bf(v.z) | ((unsigned int)f2bf(v.w) << 16);
  ((uint2*)Xb)[i] = o;
}

// ------------------------------------------------------------ weights -> bf16, concat [Wl | Wr]
__global__ __launch_bounds__(256) void k_cvt_w(const float* __restrict__ W1l,
                                               const float* __restrict__ W1r,
                                               const float* __restrict__ W2l,
                                               const float* __restrict__ W2r,
                                               unsigned short* __restrict__ Wb1,
                                               unsigned short* __restrict__ Wb2) {
  int i = blockIdx.x * 256 + threadIdx.x;
  if (i < 128 * 256) {
    int o = i >> 8, k = i & 255;
    float v = (k < 128) ? W1l[o * 128 + k] : W1r[o * 128 + (k - 128)];
    Wb1[i] = f2bf(v);
  } else if (i < 128 * 256 + 64 * 256) {
    int j = i - 128 * 256;
    int o = j >> 8, k = j & 255;
    float v = (k < 128) ? W2l[o * 128 + k] : W2r[o * 128 + (k - 128)];
    Wb2[j] = f2bf(v);
  }
}

// ------------------------------------------------------------ gather + mean (bf16 in/out)
// one wave per node; lane holds 2 channels (one packed uint); fp32 accumulate
__global__ __launch_bounds__(256) void k_gather(const unsigned short* __restrict__ Xb,
                                                const int* __restrict__ row_off,
                                                const int* __restrict__ csr,
                                                unsigned short* __restrict__ aggb, int n) {
  const int lane = threadIdx.x & 63;
  const int node = blockIdx.x * 4 + __builtin_amdgcn_readfirstlane(threadIdx.x >> 6);
  if (node >= n) return;
  const int rs = row_off[node];
  const int re = row_off[node + 1];
  const unsigned int* Xp = (const unsigned int*)Xb;
  float ax = 0.0f, ay = 0.0f;
  int e = rs;
  for (; e + 4 <= re; e += 4) {
    int s0 = csr[e + 0], s1 = csr[e + 1], s2 = csr[e + 2], s3 = csr[e + 3];
    unsigned int a = Xp[(size_t)s0 * 64 + lane];
    unsigned int b = Xp[(size_t)s1 * 64 + lane];
    unsigned int c = Xp[(size_t)s2 * 64 + lane];
    unsigned int d = Xp[(size_t)s3 * 64 + lane];
    ax += (bflo(a) + bflo(b)) + (bflo(c) + bflo(d));
    ay += (bfhi(a) + bfhi(b)) + (bfhi(c) + bfhi(d));
  }
  for (; e < re; ++e) {
    unsigned int a = Xp[(size_t)csr[e] * 64 + lane];
    ax += bflo(a);
    ay += bfhi(a);
  }
  const float invd = 1.0f / fmaxf((float)(re - rs), 1.0f);
  unsigned int o = (unsigned int)f2bf(ax * invd) | ((unsigned int)f2bf(ay * invd) << 16);
  ((unsigned int*)aggb)[(size_t)node * 64 + lane] = o;
}

// ------------------------------------------------------------- layer 1 (MFMA)
// h = relu([agg | x] @ Wb1^T + b1), output bf16.
// Block = 4 waves; wave w owns rows [b*64 + w*16, +16), loops 8 col-tiles of 16.
// 16x16x32 bf16 MFMA: A row = lane&15, k-sub = (lane>>4)*8; C/D col = lane&15,
// row = (lane>>4)*4 + v  [HW-verified mapping].
__global__ __launch_bounds__(256) void k_gemm1(
    const unsigned short* __restrict__ aggb, const unsigned short* __restrict__ xb,
    const unsigned short* __restrict__ Wb,   // [128][256]
    const float* __restrict__ bias,
    unsigned short* __restrict__ hb, int nRows)
{
  const int lane = threadIdx.x & 63;
  const int w = threadIdx.x >> 6;
  const int lr = lane & 15;
  const int kg = lane >> 4;
  const int r0 = blockIdx.x * 64 + w * 16;
  int arow = r0 + lr;
  if (arow >= nRows) arow = nRows - 1;   // clamp loads; stores guarded

  f32x4 acc[8];
#pragma unroll
  for (int ct = 0; ct < 8; ++ct) acc[ct] = (f32x4)(0.0f);

#pragma unroll
  for (int kc = 0; kc < 4; ++kc) {
    short8 af = *(const short8*)(aggb + (size_t)arow * 128 + kc * 32 + kg * 8);
#pragma unroll
    for (int ct = 0; ct < 8; ++ct) {
      short8 bfr = *(const short8*)(Wb + (size_t)(ct * 16 + lr) * 256 + kc * 32 + kg * 8);
      acc[ct] = __builtin_amdgcn_mfma_f32_16x16x32_bf16(af, bfr, acc[ct], 0, 0, 0);
    }
  }
#pragma unroll
  for (int kc = 0; kc < 4; ++kc) {
    short8 af = *(const short8*)(xb + (size_t)arow * 128 + kc * 32 + kg * 8);
#pragma unroll
    for (int ct = 0; ct < 8; ++ct) {
      short8 bfr = *(const short8*)(Wb + (size_t)(ct * 16 + lr) * 256 + 128 + kc * 32 + kg * 8);
      acc[ct] = __builtin_amdgcn_mfma_f32_16x16x32_bf16(af, bfr, acc[ct], 0, 0, 0);
    }
  }

#pragma unroll
  for (int ct = 0; ct < 8; ++ct) {
    const int col = ct * 16 + lr;
    const float b = bias[col];
#pragma unroll
    for (int v = 0; v < 4; ++v) {
      int row = r0 + kg * 4 + v;
      if (row < nRows) {
        float o = fmaxf(acc[ct][v] + b, 0.0f);
        hb[(size_t)row * 128 + col] = f2bf(o);
      }
    }
  }
}

// ------------------------------------------- layer 2 (MFMA) + log_softmax
// out = log_softmax([agg | h] @ Wb2^T + b2). Block = 4 waves = 64 rows;
// wave w owns rows [b*64+w*16, +16), loops 4 col-tiles (64 cols). Epilogue
// through a 16KB LDS tile; 4 threads/row reduce via shfl_xor(1,2).
__global__ __launch_bounds__(256) void k_gemm2(
    const unsigned short* __restrict__ aggb, const unsigned short* __restrict__ hb,
    const unsigned short* __restrict__ Wb,   // [64][256]
    const float* __restrict__ bias,
    float* __restrict__ OUT, int nRows)
{
  __shared__ float lds[64][64];

  const int lane = threadIdx.x & 63;
  const int w = threadIdx.x >> 6;
  const int lr = lane & 15;
  const int kg = lane >> 4;
  const int r0b = blockIdx.x * 64;
  const int r0 = r0b + w * 16;
  int arow = r0 + lr;
  if (arow >= nRows) arow = nRows - 1;

  f32x4 acc[4];
#pragma unroll
  for (int ct = 0; ct < 4; ++ct) acc[ct] = (f32x4)(0.0f);

#pragma unroll
  for (int kc = 0; kc < 4; ++kc) {
    short8 af = *(const short8*)(aggb + (size_t)arow * 128 + kc * 32 + kg * 8);
#pragma unroll
    for (int ct = 0; ct < 4; ++ct) {
      short8 bfr = *(const short8*)(Wb + (size_t)(ct * 16 + lr) * 256 + kc * 32 + kg * 8);
      acc[ct] = __builtin_amdgcn_mfma_f32_16x16x32_bf16(af, bfr, acc[ct], 0, 0, 0);
    }
  }
#pragma unroll
  for (int kc = 0; kc < 4; ++kc) {
    short8 af = *(const short8*)(hb + (size_t)arow * 128 + kc * 32 + kg * 8);
#pragma unroll
    for (int ct = 0; ct < 4; ++ct) {
      short8 bfr = *(const short8*)(Wb + (size_t)(ct * 16 + lr) * 256 + 128 + kc * 32 + kg * 8);
      acc[ct] = __builtin_amdgcn_mfma_f32_16x16x32_bf16(af, bfr, acc[ct], 0, 0, 0);
    }
  }

#pragma unroll
  for (int ct = 0; ct < 4; ++ct) {
    const int col = ct * 16 + lr;
    const float b = bias[col];
#pragma unroll
    for (int v = 0; v < 4; ++v)
      lds[w * 16 + kg * 4 + v][col] = acc[ct][v] + b;
  }
  __syncthreads();

  const int t = threadIdx.x;
  const int row = t >> 2;         // 0..63
  const int q = t & 3;            // quarter: 16 cols
  const int grow = r0b + row;

  float vals[16];
#pragma unroll
  for (int i = 0; i < 16; ++i) vals[i] = lds[row][q * 16 + i];

  float m = vals[0];
#pragma unroll
  for (int i = 1; i < 16; ++i) m = fmaxf(m, vals[i]);
  m = fmaxf(m, __shfl_xor(m, 1));
  m = fmaxf(m, __shfl_xor(m, 2));

  float s = 0.0f;
#pragma unroll
  for (int i = 0; i < 16; ++i) s += __expf(vals[i] - m);
  s += __shfl_xor(s, 1);
  s += __shfl_xor(s, 2);
  const float lse = m + __logf(s);

  if (grow < nRows) {
    float* orow = OUT + (size_t)grow * 64 + q * 16;
#pragma unroll
    for (int i = 0; i < 4; ++i) {
      float4 o;
      o.x = vals[4*i+0] - lse; o.y = vals[4*i+1] - lse;
      o.z = vals[4*i+2] - lse; o.w = vals[4*i+3] - lse;
      ((float4*)orow)[i] = o;
    }
  }
}

// ----------------------------------------------------------------- launch
extern "C" void kernel_launch(void* const* d_in, const int* in_sizes, int n_in,
                              void* d_out, int out_size, void* d_ws, size_t ws_size,
                              hipStream_t stream) {
  const float* x   = (const float*)d_in[0];
  const int*   ei  = (const int*)d_in[1];
  const float* W1l = (const float*)d_in[2];
  const float* W1r = (const float*)d_in[3];
  const float* b1  = (const float*)d_in[4];
  const float* W2l = (const float*)d_in[5];
  const float* W2r = (const float*)d_in[6];
  const float* b2  = (const float*)d_in[7];
  float* out = (float*)d_out;

  const int N  = in_sizes[0] / IN_C;      // 50000
  const int nE = in_sizes[1] / 2;         // 800000
  const int* src = ei;
  const int* dst = ei + nE;

  const int NB = (N + SCAN_BLK - 1) / SCAN_BLK;   // 196

  char* w = (char*)d_ws;
  size_t off = 0;
  int* row_off = (int*)(w + off); off += ((size_t)(N + 1) * 4 + 255) & ~255ull;
  int* cnt     = (int*)(w + off); off += ((size_t)N * 4 + 255) & ~255ull;       // count, then cursor
  int* partial = (int*)(w + off); off += 1024;
  int* csr     = (int*)(w + off); off += (size_t)nE * 4;
  unsigned short* xb   = (unsigned short*)(w + off); off += (size_t)N * 128 * 2;
  unsigned short* hb   = (unsigned short*)(w + off); off += (size_t)N * 128 * 2;
  unsigned short* aggb = (unsigned short*)(w + off); off += (size_t)N * 128 * 2;
  unsigned short* Wb1  = (unsigned short*)(w + off); off += 128 * 256 * 2;
  unsigned short* Wb2  = (unsigned short*)(w + off); off += 64 * 256 * 2;

  hipMemsetAsync(cnt, 0, (size_t)N * 4, stream);

  // --- build CSR (dst-bucketed src lists) ---
  k_count<<<(nE + 255) / 256, 256, 0, stream>>>(dst, cnt, nE);
  k_scan1<<<NB, SCAN_BLK, 0, stream>>>(cnt, row_off, partial, N);
  k_scan2<<<1, SCAN_BLK, 0, stream>>>(partial, NB);
  k_scan3<<<NB, SCAN_BLK, 0, stream>>>(row_off, cnt, partial, N);
  k_fill<<<(nE + 255) / 256, 256, 0, stream>>>(src, dst, cnt, csr, nE);

  // --- bf16 conversions ---
  k_cvt_x<<<(N * 128 / 4 + 255) / 256, 256, 0, stream>>>(x, xb, N * 128 / 4);
  k_cvt_w<<<(192 * 256 + 255) / 256, 256, 0, stream>>>(W1l, W1r, W2l, W2r, Wb1, Wb2);

  // --- layer 1 ---
  k_gather<<<(N + 3) / 4, 256, 0, stream>>>(xb, row_off, csr, aggb, N);
  k_gemm1<<<(N + 63) / 64, 256, 0, stream>>>(aggb, xb, Wb1, b1, hb, N);

  // --- layer 2 ---
  k_gather<<<(N + 3) / 4, 256, 0, stream>>>(hb, row_off, csr, aggb, N);
  k_gemm2<<<(N + 63) / 64, 256, 0, stream>>>(aggb, hb, Wb2, b2, out, N);
}